// Round 4
// baseline (487.214 us; speedup 1.0000x reference)
//
#include <hip/hip_runtime.h>

// Spiking LIF forward scan, LDS-staged + non-temporal global access,
// fully-unrolled software pipeline (static waitcnt counts).
//
// x: (B=128, C=512, T=1024) fp32, t contiguous. beta scalar, Vth per channel.
// Recurrence per (b,c) row is strictly sequential in t (Heaviside spike);
// parallelism = B*C = 65536 rows = 1024 waves = 4 waves/CU (structural).
//
// Round-3 lesson: byte counts were ideal (FETCH 131 MB via L3, WRITE 262 MB)
// but BW sat at 2.37 TB/s ~= one vmem op in flight per wave. Diagnosis: the
// data-dependent guards (`if (k+3 < NT) issue_loads...`) make the number of
// outstanding vmem ops path-dependent, so the waitcnt pass emits conservative
// ~vmcnt(0) drains at every write_lds -> full queue drain per iteration ->
// latency-serialized. Fix: #pragma unroll the pipeline loop so guards
// constant-fold, vmem issue is straight-line, and precise vmcnt(N) waits
// retire only the 16 oldest loads while stores + deeper prefetch stay in
// flight.
//
// One wave (64 threads) per block, 64 rows/block. Double-buffered LDS tiles
// (2 x 16 KB) + two register prefetch buffers -> 32 KB global loads in
// flight per wave during compute.
//
// LDS swizzle (4-float groups, preserves b128):
//   idx(row, t) = row*64 + ((t>>2) ^ (row & 15))*4 + (t & 3)
// Both phases hit the 8-words/bank balanced floor; measured
// SQ_LDS_BANK_CONFLICT = 0.

#define LIF_BC 65536
#define LIF_T  1024
#define TT     64            // time-steps per tile
#define NT     (LIF_T / TT)  // 16 tiles
#define ROWS   64            // rows per block == wave size

using fvec4 = __attribute__((ext_vector_type(4))) float;

__global__ __launch_bounds__(64) void lif_fwd(
    const float* __restrict__ x,
    const float* __restrict__ beta_p,
    const float* __restrict__ vth_p,
    float* __restrict__ out)
{
    __shared__ float lds0[ROWS * TT];
    __shared__ float lds1[ROWS * TT];

    const int lane = threadIdx.x;        // 0..63
    const int r0   = blockIdx.x * ROWS;  // first (b*C+c) row of this block

    const float beta = beta_p[0];
    const float vth  = vth_p[(r0 + lane) & 511];  // C = 512 (pow2)

    // load/store phase mapping: lane -> (row quad offset, 4-float group)
    const int l_row4 = lane >> 4;  // 0..3
    const int l_t    = lane & 15;  // group index within row

    fvec4 pf0[16], pf1[16];  // two tile-deep prefetch buffers (128 VGPRs)

    // 16 nt loads for tile `tile` (each instr: 4 rows x 256 B contiguous).
    auto issue_loads = [&](fvec4 (&pf)[16], int tile) {
#pragma unroll
        for (int j = 0; j < 16; ++j) {
            const int row = 4 * j + l_row4;
            pf[j] = __builtin_nontemporal_load(
                (const fvec4*)&x[(size_t)(r0 + row) * LIF_T
                                 + (size_t)tile * TT + l_t * 4]);
        }
    };

    // Drain a prefetch buffer into an LDS tile (swizzled b128 writes).
    auto write_lds = [&](float* buf, fvec4 (&pf)[16]) {
#pragma unroll
        for (int j = 0; j < 16; ++j) {
            const int row  = 4 * j + l_row4;
            const int slot = l_t ^ (row & 15);
            *(fvec4*)&buf[row * TT + slot * 4] = pf[j];
        }
    };

    float mem = 0.0f, spk = 0.0f;

    // 64 recurrence steps for this lane's row; spikes overwrite x in place.
    // Bit-exact fp32 op order vs the numpy reference:
    //   rst = spk*Vth; mem = ((mem*beta) + x) - rst; spk = (mem - Vth) > 0.
    // __f*_rn blocks -ffp-contract FMA fusion (1-ulp drift flips a spike).
    auto compute = [&](float* buf) {
        const int rbase = lane * TT;
        const int sw    = lane & 15;
#pragma unroll
        for (int g = 0; g < 16; ++g) {
            fvec4 v = *(fvec4*)&buf[rbase + (g ^ sw) * 4];
#pragma unroll
            for (int e = 0; e < 4; ++e) {
                float rst = __fmul_rn(spk, vth);
                mem = __fsub_rn(__fadd_rn(__fmul_rn(mem, beta), v[e]), rst);
                spk = (__fsub_rn(mem, vth) > 0.0f) ? 1.0f : 0.0f;
                v[e] = spk;
            }
            *(fvec4*)&buf[rbase + (g ^ sw) * 4] = v;
        }
    };

    // Gather spikes from LDS and stream (nt) to global, coalesced.
    auto store_tile = [&](const float* buf, int tile) {
#pragma unroll
        for (int j = 0; j < 16; ++j) {
            const int row  = 4 * j + l_row4;
            const int slot = l_t ^ (row & 15);
            fvec4 s = *(const fvec4*)&buf[row * TT + slot * 4];
            __builtin_nontemporal_store(
                s, (fvec4*)&out[(size_t)(r0 + row) * LIF_T
                                + (size_t)tile * TT + l_t * 4]);
        }
    };

    // ---- software pipeline: 2 tiles of loads in flight during compute ----
    // FULLY UNROLLED (8 static iterations): every guard below constant-folds,
    // so the vmem instruction stream is straight-line and the waitcnt pass
    // emits precise vmcnt(N) waits (retire only the needed 16 loads) instead
    // of conservative queue drains.
    issue_loads(pf0, 0);
    issue_loads(pf1, 1);
    write_lds(lds0, pf0);   // waits tile-0 loads (vmcnt issue-ordered)
    issue_loads(pf0, 2);

#pragma unroll
    for (int k = 0; k < NT; k += 2) {
        // even tile k (lds0 / pf0 side)
        compute(lds0);
        store_tile(lds0, k);                            // nt stores, fire & forget
        write_lds(lds1, pf1);                           // tile k+1 regs -> LDS
        if (k + 3 < NT) issue_loads(pf1, k + 3);
        // odd tile k+1 (lds1 / pf1 side)
        compute(lds1);
        store_tile(lds1, k + 1);
        if (k + 2 < NT) write_lds(lds0, pf0);           // tile k+2 regs -> LDS
        if (k + 4 < NT) issue_loads(pf0, k + 4);
    }
}

extern "C" void kernel_launch(void* const* d_in, const int* in_sizes, int n_in,
                              void* d_out, int out_size, void* d_ws, size_t ws_size,
                              hipStream_t stream) {
    const float* x    = (const float*)d_in[0];  // (B, C, T) fp32
    const float* beta = (const float*)d_in[1];  // scalar
    const float* vth  = (const float*)d_in[2];  // (C,) fp32
    float* out = (float*)d_out;                 // (B, C, T) fp32

    dim3 grid(LIF_BC / ROWS);                   // 1024 one-wave blocks
    lif_fwd<<<grid, 64, 0, stream>>>(x, beta, vth, out);
}

// Round 5
// 482.819 us; speedup vs baseline: 1.0091x; 1.0091x over previous
//
#include <hip/hip_runtime.h>

// Spiking LIF forward scan — producer/consumer wave specialization.
//
// x: (B=128, C=512, T=1024) fp32, t contiguous. beta scalar, Vth per channel.
// Recurrence per (b,c) row is strictly sequential in t; parallelism = 65536
// rows. One thread per row => compute occupancy is capped at 1024 waves.
//
// Rounds 1-4 lesson: any single wave that both loads and stores serializes on
// its IN-ORDER vmcnt queue — consuming tile-k loads forces retirement of
// tile-(k-1) nt stores (HBM ack, us-scale under congestion) -> ~10 us/tile,
// ~2.4 TB/s, while the harness's own fill kernel does 6.5 TB/s. Per-wave MLP
// cannot be fixed by wait placement; the roles must be split.
//
// Structure: 256 blocks x 512 threads (8 waves) = 8 waves/CU, 1 block/CU
// (128 KB LDS forbids 2). Per block: 256 rows.
//   waves 0-3: compute. LDS-only. Own 64 rows each; carry (mem,spk) in regs.
//   waves 4-5: loaders. global_load_lds (16 B/lane, no VGPR payload, async)
//              for alternate tiles; wait own vmcnt; flag READY.
//   waves 6-7: storers. ds_read spikes -> nontemporal global stores for
//              alternate tiles. NEVER wait on vmcnt -> store acks can't
//              serialize anything.
// Sync: LDS mailbox flags + workgroup acquire/release atomics. NO
// __syncthreads in the pipeline (it would force vmcnt(0) drains on the
// storers and re-couple them).
//
// Tiles: 32 t-steps (256 rows x 32 t x 4 B = 32 KB). 4 buffers = 4-tile
// lookahead. Buffer lifecycle: FREE ->(loader)-> READY ->(4 computes)->
// SPIKES ->(storer)-> FREE; monotone counters, no ABA.
//
// global_load_lds forces LDS slot16 = j*64 + lane. Loader lane l of instr j
// fetches (row = 8j + (l>>3), group g = (l&7) ^ (l>>3)), so the landed
// layout IS the swizzle slot(row, g) = row*8 + (g ^ (row&7)): compute and
// storer phases keep the measured-0-conflict balanced 8-words/bank pattern,
// and each 8-lane group still covers one contiguous 128 B global segment
// (permuted within it — coalescing intact).

#define LIF_T   1024
#define TT      32               // t-steps per tile
#define NTILES  (LIF_T / TT)     // 32
#define RPB     256              // rows per block
#define NBUF    4
#define BUF_FLOATS (RPB * TT)    // 8192 floats = 32 KB

using fvec4 = __attribute__((ext_vector_type(4))) float;

__global__ __launch_bounds__(512) void lif_fwd(
    const float* __restrict__ x,
    const float* __restrict__ beta_p,
    const float* __restrict__ vth_p,
    float* __restrict__ out)
{
    __shared__ float buf[NBUF][BUF_FLOATS];   // 128 KB
    __shared__ int ready_flag[NBUF];          // = k+1 when tile k landed
    __shared__ int done_cnt[NBUF];            // accumulating: +1 per compute wave
    __shared__ int free_cnt[NBUF];            // accumulating: +1 per store pass

    const int tid  = threadIdx.x;
    const int lane = tid & 63;
    const int wid  = tid >> 6;                // 0..7
    const int r0   = blockIdx.x * RPB;

    if (tid < NBUF) { ready_flag[tid] = 0; done_cnt[tid] = 0; free_cnt[tid] = 0; }
    __syncthreads();  // once, at start — harmless drain

    if (wid < 4) {
        // ---------------- compute waves ----------------
        const int   r    = (wid << 6) | lane;          // row within block
        const float beta = beta_p[0];
        const float vth  = vth_p[(r0 + r) & 511];      // C = 512
        const int   sw   = r & 7;                      // swizzle key
        float mem = 0.0f, spk = 0.0f;

        for (int k = 0; k < NTILES; ++k) {
            const int b = k & (NBUF - 1);
            while (__hip_atomic_load(&ready_flag[b], __ATOMIC_ACQUIRE,
                                     __HIP_MEMORY_SCOPE_WORKGROUP) != k + 1)
                __builtin_amdgcn_s_sleep(1);

            float* rowp = &buf[b][r * TT];
#pragma unroll
            for (int g = 0; g < 8; ++g) {
                fvec4 v = *(fvec4*)&rowp[(g ^ sw) << 2];
                // Bit-exact fp32 order vs numpy reference:
                //   rst = spk*Vth; mem = ((mem*beta)+x) - rst;
                //   spk = (mem - Vth) > 0.  __f*_rn blocks FMA contraction
                //   (1-ulp drift flips a spike).
#pragma unroll
                for (int e = 0; e < 4; ++e) {
                    float rst = __fmul_rn(spk, vth);
                    mem = __fsub_rn(__fadd_rn(__fmul_rn(mem, beta), v[e]), rst);
                    spk = (__fsub_rn(mem, vth) > 0.0f) ? 1.0f : 0.0f;
                    v[e] = spk;
                }
                *(fvec4*)&rowp[(g ^ sw) << 2] = v;     // spikes in place
            }
            if (lane == 0)
                __hip_atomic_fetch_add(&done_cnt[b], 1, __ATOMIC_RELEASE,
                                       __HIP_MEMORY_SCOPE_WORKGROUP);
        }
    } else if (wid < 6) {
        // ---------------- loader waves (global -> LDS, async) ----------------
        const int par = wid - 4;               // tile parity
        const int jr  = lane >> 3;             // row-within-instruction 0..7
        const int g   = (lane & 7) ^ jr;       // permuted 16 B group

        for (int k = par; k < NTILES; k += 2) {
            const int b = k & (NBUF - 1);
            while (__hip_atomic_load(&free_cnt[b], __ATOMIC_ACQUIRE,
                                     __HIP_MEMORY_SCOPE_WORKGROUP) != (k >> 2))
                __builtin_amdgcn_s_sleep(1);

#pragma unroll
            for (int j = 0; j < 32; ++j) {
                const int r = (j << 3) | jr;
                const float* gsrc =
                    &x[(size_t)(r0 + r) * LIF_T + k * TT + (g << 2)];
                // 16 B/lane, dest = uniform base + lane*16. aux=2 -> NT
                // (evict-first: L3 hits still served, no fresh allocation ->
                //  no eviction of harness dirty lines; round-3 verified).
                __builtin_amdgcn_global_load_lds(
                    (const __attribute__((address_space(1))) unsigned int*)gsrc,
                    (__attribute__((address_space(3))) unsigned int*)&buf[b][j << 8],
                    16, 0, 2);
            }
            __builtin_amdgcn_s_waitcnt(0);     // own loads only: data landed
            if (lane == 0)
                __hip_atomic_store(&ready_flag[b], k + 1, __ATOMIC_RELEASE,
                                   __HIP_MEMORY_SCOPE_WORKGROUP);
        }
    } else {
        // ---------------- storer waves (LDS -> global, fire & forget) --------
        const int par = wid - 6;
        const int jr  = lane >> 3;
        const int gp  = (lane & 7) ^ jr;       // swizzled LDS slot for group lane&7

        for (int k = par; k < NTILES; k += 2) {
            const int b    = k & (NBUF - 1);
            const int want = ((k >> 2) + 1) * 4;
            while (__hip_atomic_load(&done_cnt[b], __ATOMIC_ACQUIRE,
                                     __HIP_MEMORY_SCOPE_WORKGROUP) != want)
                __builtin_amdgcn_s_sleep(1);

#pragma unroll
            for (int j = 0; j < 32; ++j) {
                const int r = (j << 3) | jr;
                fvec4 s = *(fvec4*)&buf[b][r * TT + (gp << 2)];
                __builtin_nontemporal_store(
                    s, (fvec4*)&out[(size_t)(r0 + r) * LIF_T + k * TT
                                    + ((lane & 7) << 2)]);
            }
            // Signal FREE: needs only the ds_reads complete (release waits
            // lgkmcnt). The nt stores stay in flight — nothing ever waits
            // on this wave's vmcnt.
            if (lane == 0)
                __hip_atomic_fetch_add(&free_cnt[b], 1, __ATOMIC_RELEASE,
                                       __HIP_MEMORY_SCOPE_WORKGROUP);
        }
    }
}

extern "C" void kernel_launch(void* const* d_in, const int* in_sizes, int n_in,
                              void* d_out, int out_size, void* d_ws, size_t ws_size,
                              hipStream_t stream) {
    const float* x    = (const float*)d_in[0];  // (B, C, T) fp32
    const float* beta = (const float*)d_in[1];  // scalar
    const float* vth  = (const float*)d_in[2];  // (C,) fp32
    float* out = (float*)d_out;                 // (B, C, T) fp32

    dim3 grid(65536 / RPB);                     // 256 blocks x 512 threads
    lif_fwd<<<grid, 512, 0, stream>>>(x, beta, vth, out);
}